// Round 9
// baseline (433.094 us; speedup 1.0000x reference)
//
#include <hip/hip_runtime.h>
#include <hip/hip_bf16.h>

typedef short    short8  __attribute__((ext_vector_type(8)));
typedef unsigned uint2v  __attribute__((ext_vector_type(2)));
typedef float    f32x4   __attribute__((ext_vector_type(4)));

#define B_TOT 4096
#define SEQ   256
#define NDOF  7
#define HDIM  256
#define ROWS  16
#define DTF   0.002f

// RNE float->bf16 (setup only)
static __device__ __forceinline__ unsigned short f2bf(float f) {
    union { float f; unsigned u; } u; u.f = f;
    unsigned x = u.u;
    unsigned r = (x + 0x7FFFu + ((x >> 16) & 1u)) >> 16;
    return (unsigned short)r;
}
static __device__ __forceinline__ unsigned cvt_pk_bf16(float lo, float hi) {
    unsigned r;
    asm("v_cvt_pk_bf16_f32 %0, %1, %2" : "=v"(r) : "v"(lo), "v"(hi));
    return r;
}
static __device__ __forceinline__ float silu(float p) {
    return p * __builtin_amdgcn_rcpf(1.0f + __expf(-p));
}

__global__ __launch_bounds__(512, 2)
void NeuralODE_kernel(const float* __restrict__ st0, const float* __restrict__ tq,
                      const float* __restrict__ W1,  const float* __restrict__ b1,
                      const float* __restrict__ W2,  const float* __restrict__ b2,
                      const float* __restrict__ W3,  const float* __restrict__ b3,
                      float* __restrict__ out)
{
    __shared__ __align__(16) short h1b[16 * 264];
    __shared__ __align__(16) short h2b[16 * 264];

    const int tid  = threadIdx.x;
    const int w    = tid >> 6;          // 8 waves
    const int lane = tid & 63;
    const int g    = lane >> 4;
    const int n    = lane & 15;
    const int b0   = blockIdx.x * ROWS;
    const int mb   = 32 * w;
    const int bp32 = ((lane ^ 32) & 63) << 2;   // ds_bpermute byte index: lane^32

    // ---- fused L1 matrices, channel layout:
    // k0-3=q0-3, k4-7=w0-3, k8-10=q4-6, k11=bias, k12-14=w4-6, k15=0,
    // k16-19=a0-3, k20-23=tau0-3, k24-26=a4-6, k27=0, k28-30=tau4-6, k31=0
    // p1 = A q + E w + G a + C tau + b1;  E = alpha*A + B, G = beta*B
    auto mk_small = [&](float alpha, float beta, short8* fr2) {
#pragma unroll
        for (int t = 0; t < 2; ++t) {
            short8 fr;
#pragma unroll
            for (int j = 0; j < 8; ++j) {
                int k = 8 * g + j;
                int m = mb + 16 * t + n;
                float val;
                if (k < 4)        val = W1[k * HDIM + m];                               // A d=k
                else if (k < 8)   val = alpha * W1[(k - 4) * HDIM + m]
                                      + W1[(k + 3) * HDIM + m];                         // E d=k-4
                else if (k < 11)  val = W1[(k - 4) * HDIM + m];                         // A d=4..6
                else if (k == 11) val = b1[m];
                else if (k < 15)  val = alpha * W1[(k - 8) * HDIM + m]
                                      + W1[(k - 1) * HDIM + m];                         // E d=4..6
                else if (k == 15) val = 0.0f;
                else if (k < 20)  val = beta * W1[(k - 9) * HDIM + m];                  // G d=k-16
                else if (k < 24)  val = W1[(k - 6) * HDIM + m];                         // C d=k-20
                else if (k < 27)  val = beta * W1[(k - 13) * HDIM + m];                 // G d=4..6
                else if (k == 27) val = 0.0f;
                else if (k < 31)  val = W1[(k - 10) * HDIM + m];                        // C d=4..6
                else              val = 0.0f;
                fr[j] = (short)f2bf(val);
            }
            fr2[t] = fr;
        }
    };
    short8 s0f[2], sxf[2];
    mk_small(0.0f, 0.0f, s0f);        // prologue (x: q,v0,0,tau)
    mk_small(DTF, 0.5f * DTF, sxf);   // steady state

    short8 a2f[2][8];
#pragma unroll
    for (int t = 0; t < 2; ++t)
#pragma unroll
        for (int ks = 0; ks < 8; ++ks) {
            short8 fr;
#pragma unroll
            for (int j = 0; j < 8; ++j) {
                int k = 32 * ks + 8 * g + j;
                fr[j] = (short)f2bf(W2[(size_t)k * HDIM + mb + 16 * t + n]);
            }
            a2f[t][ks] = fr;
        }
    // W3^T frags: FULL K in every wave (redundant L3 -> no red buffer, no 3rd barrier)
    short8 a3f[8];
#pragma unroll
    for (int ks = 0; ks < 8; ++ks) {
        short8 fr;
#pragma unroll
        for (int j = 0; j < 8; ++j) {
            int k = 32 * ks + 8 * g + j;
            fr[j] = (n < NDOF) ? (short)f2bf(W3[k * NDOF + n]) : (short)0;
        }
        a3f[ks] = fr;
    }
    f32x4 b2v[2];
#pragma unroll
    for (int t = 0; t < 2; ++t) {
        int m = mb + 16 * t + 4 * g;
        f32x4 tv; tv[0] = b2[m]; tv[1] = b2[m + 1]; tv[2] = b2[m + 2]; tv[3] = b2[m + 3];
        b2v[t] = tv;
    }
    f32x4 b3v;
#pragma unroll
    for (int r = 0; r < 4; ++r) {
        int m = 4 * g + r;
        b3v[r] = (m < NDOF) ? b3[m] : 0.0f;
    }

    // ---- state: lane (g,n), g<2, owns dofs d = 4g+r (matches L3 C-layout) ----
    f32x4 q, wv, a;
    const float* sp = st0 + (size_t)(b0 + n) * 14;
#pragma unroll
    for (int r = 0; r < 4; ++r) {
        int d = 4 * g + r;
        bool val = (g < 2) && (d < NDOF);
        q[r]  = val ? sp[d] : 0.0f;
        wv[r] = val ? sp[7 + d] : 0.0f;   // v0 initially; becomes half-kick w
        a[r]  = 0.0f;
    }
    float tn[4];
    tn[0] = tn[1] = tn[2] = tn[3] = 0.0f;

    const float* tqb = tq + (size_t)(b0 + n) * (SEQ * NDOF) + ((g == 3) ? 4 : 0);
    auto pf_tau = [&](int idx) {
        if (g >= 2) {
            const float* tp = tqb + idx * NDOF;
            tn[0] = tp[0]; tn[1] = tp[1]; tn[2] = tp[2];
            tn[3] = (g == 2) ? tp[3] : 0.0f;
        }
    };

    // ---- register-only x-fragment build (one bpermute pair on the chain) ----
    auto build_xf = [&]() -> short8 {
        float hi1 = (g == 1) ? 1.0f : q[3];
        unsigned qw0 = cvt_pk_bf16(q[0], q[1]),   qw1 = cvt_pk_bf16(q[2], hi1);
        unsigned ww0 = cvt_pk_bf16(wv[0], wv[1]), ww1 = cvt_pk_bf16(wv[2], wv[3]);
        unsigned aw0 = cvt_pk_bf16(a[0], a[1]),   aw1 = cvt_pk_bf16(a[2], a[3]);
        unsigned r0 = (unsigned)__builtin_amdgcn_ds_bpermute(bp32, (int)aw0);
        unsigned r1 = (unsigned)__builtin_amdgcn_ds_bpermute(bp32, (int)aw1);
        unsigned tw0 = cvt_pk_bf16(tn[0], tn[1]), tw1 = cvt_pk_bf16(tn[2], tn[3]);
        union { unsigned u[4]; short8 s; } xu;
        xu.u[0] = (g < 2) ? qw0 : r0;
        xu.u[1] = (g < 2) ? qw1 : r1;
        xu.u[2] = (g < 2) ? ww0 : tw0;
        xu.u[3] = (g < 2) ? ww1 : tw1;
        return xu.s;
    };

    short* h1w = &h1b[n * 264 + mb];
    short* h2w = &h2b[n * 264 + mb];
    const short* h1r = &h1b[n * 264 + 8 * g];
    const short* h2r = &h2b[n * 264 + 8 * g];

    auto accel = [&](short8 xf, const short8* sf) -> f32x4 {
        const f32x4 cz = {0.0f, 0.0f, 0.0f, 0.0f};
        // L1
        f32x4 c1a = __builtin_amdgcn_mfma_f32_16x16x32_bf16(sf[0], xf, cz, 0, 0, 0);
        f32x4 c1b = __builtin_amdgcn_mfma_f32_16x16x32_bf16(sf[1], xf, cz, 0, 0, 0);
        {
            uint2v p;
            p[0] = cvt_pk_bf16(silu(c1a[0]), silu(c1a[1]));
            p[1] = cvt_pk_bf16(silu(c1a[2]), silu(c1a[3]));
            *(uint2v*)&h1w[4 * g] = p;
            p[0] = cvt_pk_bf16(silu(c1b[0]), silu(c1b[1]));
            p[1] = cvt_pk_bf16(silu(c1b[2]), silu(c1b[3]));
            *(uint2v*)&h1w[16 + 4 * g] = p;
        }
        __syncthreads();   // B1: h1 complete (also fences prev-eval h2 reads)

        // L2: 4 accumulator chains, depth 4
        f32x4 c2a0 = b2v[0], c2a1 = cz, c2b0 = b2v[1], c2b1 = cz;
#pragma unroll
        for (int ks = 0; ks < 4; ++ks) {
            short8 be = *(const short8*)&h1r[32 * ks];
            short8 bo = *(const short8*)&h1r[32 * (ks + 4)];
            c2a0 = __builtin_amdgcn_mfma_f32_16x16x32_bf16(a2f[0][ks],     be, c2a0, 0, 0, 0);
            c2b0 = __builtin_amdgcn_mfma_f32_16x16x32_bf16(a2f[1][ks],     be, c2b0, 0, 0, 0);
            c2a1 = __builtin_amdgcn_mfma_f32_16x16x32_bf16(a2f[0][ks + 4], bo, c2a1, 0, 0, 0);
            c2b1 = __builtin_amdgcn_mfma_f32_16x16x32_bf16(a2f[1][ks + 4], bo, c2b1, 0, 0, 0);
        }
        f32x4 c2a = c2a0 + c2a1, c2b = c2b0 + c2b1;
        {
            uint2v p;
            p[0] = cvt_pk_bf16(silu(c2a[0]), silu(c2a[1]));
            p[1] = cvt_pk_bf16(silu(c2a[2]), silu(c2a[3]));
            *(uint2v*)&h2w[4 * g] = p;
            p[0] = cvt_pk_bf16(silu(c2b[0]), silu(c2b[1]));
            p[1] = cvt_pk_bf16(silu(c2b[2]), silu(c2b[3]));
            *(uint2v*)&h2w[16 + 4 * g] = p;
        }
        __syncthreads();   // B2: h2 complete

        // L3: full K=256 redundant per wave; C-layout lands a in state layout
        f32x4 c3a = b3v, c3b = cz;
#pragma unroll
        for (int ks = 0; ks < 4; ++ks) {
            short8 pe = *(const short8*)&h2r[32 * ks];
            short8 po = *(const short8*)&h2r[32 * (ks + 4)];
            c3a = __builtin_amdgcn_mfma_f32_16x16x32_bf16(a3f[ks],     pe, c3a, 0, 0, 0);
            c3b = __builtin_amdgcn_mfma_f32_16x16x32_bf16(a3f[ks + 4], po, c3b, 0, 0, 0);
        }
        return c3a + c3b;
    };

    // ---------------- prologue: eval 0 (S0; w-channel carries v0, a=0) ----------
    pf_tau(0);
    {
        short8 xf0 = build_xf();
        pf_tau(1);
        f32x4 a0 = accel(xf0, s0f);
#pragma unroll
        for (int r = 0; r < 4; ++r) wv[r] = wv[r] + (0.5f * DTF) * a0[r];
        a = a0;
    }

    // ---------------- 256 evals ---------------------------------------------------
    float* op = out + (size_t)(b0 + n) * SEQ * 14;

#pragma unroll 1
    for (int e = 1; e <= SEQ; ++e) {
        short8 xf = build_xf();          // uses (q,w,a)_{e-1} + tau_e

        // off critical path: q_e, next-tau prefetch
        f32x4 qn;
#pragma unroll
        for (int r = 0; r < 4; ++r) qn[r] = q[r] + DTF * wv[r];
        {
            float tt = (float)(e + 1) * DTF;
            int ns = (int)floorf(tt / DTF);
            if (ns > SEQ - 1) ns = SEQ - 1;
            pf_tau(ns);
        }

        f32x4 an = accel(xf, sxf);

        f32x4 vo;
#pragma unroll
        for (int r = 0; r < 4; ++r) {
            vo[r] = wv[r] + (0.5f * DTF) * an[r];
            wv[r] = wv[r] + DTF * an[r];
        }

        if (w == 0) {
            float* o = op + (size_t)(e - 1) * 14;
            if (g == 0) {
                *(f32x4*)(o)     = qn;
                *(f32x4*)(o + 7) = vo;
            } else if (g == 1) {
                o[4]  = qn[0]; o[5]  = qn[1]; o[6]  = qn[2];
                o[11] = vo[0]; o[12] = vo[1]; o[13] = vo[2];
            }
        }
        q = qn;
        a = an;
    }
}

extern "C" void kernel_launch(void* const* d_in, const int* in_sizes, int n_in,
                              void* d_out, int out_size, void* d_ws, size_t ws_size,
                              hipStream_t stream) {
    (void)in_sizes; (void)n_in; (void)d_ws; (void)ws_size; (void)out_size;
    const float* st0 = (const float*)d_in[0];
    const float* tq  = (const float*)d_in[1];
    const float* W1  = (const float*)d_in[2];
    const float* b1  = (const float*)d_in[3];
    const float* W2  = (const float*)d_in[4];
    const float* b2  = (const float*)d_in[5];
    const float* W3  = (const float*)d_in[6];
    const float* b3  = (const float*)d_in[7];

    NeuralODE_kernel<<<dim3(B_TOT / ROWS), dim3(512), 0, stream>>>(
        st0, tq, W1, b1, W2, b2, W3, b3, (float*)d_out);
}